// Round 1
// baseline (2412.626 us; speedup 1.0000x reference)
//
#include <hip/hip_runtime.h>
#include <hip/hip_bf16.h>
#include <math.h>

#define BB 256
#define TT 512
#define DIN 64
#define ZZ 32
#define HH 64

// h_step = DT/DISC = 0.1/10
__device__ __forceinline__ float hstep() { return 0.01f; }

// ---------------------------------------------------------------------------
// RNN kernel: one block (64 threads = 1 wave) per batch. Sequential over T,
// processing the time-reversed sequence (backward RNN), both layers fused.
// Weights staged in LDS with padded leading dims (avoid 32-way bank conflict
// on column reads). Lane l computes output j=l&31, half=l>>5; halves combine
// via __shfl_xor(acc, 32).
// ---------------------------------------------------------------------------
__global__ __launch_bounds__(64) void rnn_kernel(
    const float* __restrict__ x,
    const float* __restrict__ Wi0, const float* __restrict__ Wh0,
    const float* __restrict__ bi0, const float* __restrict__ bh0,
    const float* __restrict__ Wi1, const float* __restrict__ Wh1,
    const float* __restrict__ bi1, const float* __restrict__ bh1,
    const float* __restrict__ h0,
    float* __restrict__ rnn, float* __restrict__ out)
{
    __shared__ float sWi0[32][65];   // [j][k], pad 64->65
    __shared__ float sWh0[32][33];   // pad 32->33
    __shared__ float sWi1[32][33];
    __shared__ float sWh1[32][33];
    __shared__ float sB0[32], sB1[32];
    __shared__ float sx[64];
    __shared__ float sh0[32], sh1[32];

    const int lane = threadIdx.x;
    const int b = blockIdx.x;

    for (int e = lane; e < 32 * 64; e += 64) sWi0[e >> 6][e & 63] = Wi0[e];
    for (int e = lane; e < 32 * 32; e += 64) {
        sWh0[e >> 5][e & 31] = Wh0[e];
        sWi1[e >> 5][e & 31] = Wi1[e];
        sWh1[e >> 5][e & 31] = Wh1[e];
    }
    if (lane < 32) {
        sB0[lane] = bi0[lane] + bh0[lane];
        sB1[lane] = bi1[lane] + bh1[lane];
        sh0[lane] = h0[lane];        // layer 0 init
        sh1[lane] = h0[32 + lane];   // layer 1 init
    }
    __syncthreads();

    const int j = lane & 31;
    const int half = lane >> 5;
    const size_t xbase = (size_t)b * TT * DIN;
    const size_t rbase = (size_t)b * TT * ZZ;

    for (int s = 0; s < TT; ++s) {
        const int t = TT - 1 - s;   // consume x reversed in time
        sx[lane] = x[xbase + (size_t)t * DIN + lane];
        __syncthreads();

        // ---- layer 0: h0_new = tanh(x·Wi0^T + h0·Wh0^T + b) ----
        float a0 = 0.f, a1 = 0.f, a2 = 0.f, a3 = 0.f;
        {
            const float* wr = &sWi0[j][half * 32];
            const float* xp = &sx[half * 32];
            #pragma unroll
            for (int k = 0; k < 32; k += 4) {
                a0 = fmaf(wr[k + 0], xp[k + 0], a0);
                a1 = fmaf(wr[k + 1], xp[k + 1], a1);
                a2 = fmaf(wr[k + 2], xp[k + 2], a2);
                a3 = fmaf(wr[k + 3], xp[k + 3], a3);
            }
            const float* hr = &sWh0[j][half * 16];
            const float* hp = &sh0[half * 16];
            #pragma unroll
            for (int k = 0; k < 16; k += 4) {
                a0 = fmaf(hr[k + 0], hp[k + 0], a0);
                a1 = fmaf(hr[k + 1], hp[k + 1], a1);
                a2 = fmaf(hr[k + 2], hp[k + 2], a2);
                a3 = fmaf(hr[k + 3], hp[k + 3], a3);
            }
        }
        float acc = (a0 + a1) + (a2 + a3);
        acc += __shfl_xor(acc, 32);
        const float h0new = tanhf(acc + sB0[j]);
        __syncthreads();               // all reads of old sh0 complete
        if (half == 0) sh0[j] = h0new;
        __syncthreads();

        // ---- layer 1: h1_new = tanh(h0_new·Wi1^T + h1·Wh1^T + b) ----
        a0 = a1 = a2 = a3 = 0.f;
        {
            const float* wr = &sWi1[j][half * 16];
            const float* ip = &sh0[half * 16];
            #pragma unroll
            for (int k = 0; k < 16; k += 4) {
                a0 = fmaf(wr[k + 0], ip[k + 0], a0);
                a1 = fmaf(wr[k + 1], ip[k + 1], a1);
                a2 = fmaf(wr[k + 2], ip[k + 2], a2);
                a3 = fmaf(wr[k + 3], ip[k + 3], a3);
            }
            const float* hr = &sWh1[j][half * 16];
            const float* hp = &sh1[half * 16];
            #pragma unroll
            for (int k = 0; k < 16; k += 4) {
                a0 = fmaf(hr[k + 0], hp[k + 0], a0);
                a1 = fmaf(hr[k + 1], hp[k + 1], a1);
                a2 = fmaf(hr[k + 2], hp[k + 2], a2);
                a3 = fmaf(hr[k + 3], hp[k + 3], a3);
            }
        }
        acc = (a0 + a1) + (a2 + a3);
        acc += __shfl_xor(acc, 32);
        const float h1new = tanhf(acc + sB1[j]);
        __syncthreads();               // all reads of old sh1 complete
        if (half == 0) {
            sh1[j] = h1new;
            rnn[rbase + (size_t)t * ZZ + j] = h1new;
            if (t == TT - 1) out[rbase + (size_t)(TT - 1) * ZZ + j] = h1new;
        }
        __syncthreads();
    }
}

// ---------------------------------------------------------------------------
// ODE kernel: one thread per (b, t') row, t' in [0,510]. y state + RK4 temps
// in registers (static indexing only); hidden activations round-trip through
// a per-thread LDS slice laid out stg[neuron][tid] (conflict-free) so the
// neuron loops stay runtime loops (small code, I-cache friendly). Weights
// read via uniform indices -> scalar loads on the scalar pipe.
// ---------------------------------------------------------------------------
__device__ __forceinline__ float eluf(float v) {
    return v > 0.f ? v : expm1f(v);
}

__device__ __forceinline__ void feval(
    const float yin[32], float kout[32],
    const float* __restrict__ w1, const float* __restrict__ b1,
    const float* __restrict__ w2, const float* __restrict__ b2,
    const float* __restrict__ w3, const float* __restrict__ b3,
    float* __restrict__ stg, int tid)
{
    // layer 1: 32 -> 64, elu
    #pragma unroll 2
    for (int n = 0; n < 64; ++n) {
        float acc = b1[n];
        #pragma unroll
        for (int k = 0; k < 32; ++k) acc = fmaf(w1[n * 32 + k], yin[k], acc);
        stg[n * 128 + tid] = eluf(acc);
    }
    float h[64];
    #pragma unroll
    for (int k = 0; k < 64; ++k) h[k] = stg[k * 128 + tid];

    // layer 2: 64 -> 64, elu
    #pragma unroll 2
    for (int n = 0; n < 64; ++n) {
        float acc = b2[n];
        #pragma unroll
        for (int k = 0; k < 64; ++k) acc = fmaf(w2[n * 64 + k], h[k], acc);
        stg[n * 128 + tid] = eluf(acc);
    }
    #pragma unroll
    for (int k = 0; k < 64; ++k) h[k] = stg[k * 128 + tid];

    // layer 3: 64 -> 32, linear
    #pragma unroll 2
    for (int n = 0; n < 32; ++n) {
        float acc = b3[n];
        #pragma unroll
        for (int k = 0; k < 64; ++k) acc = fmaf(w3[n * 64 + k], h[k], acc);
        stg[n * 128 + tid] = acc;
    }
    #pragma unroll
    for (int k = 0; k < 32; ++k) kout[k] = stg[k * 128 + tid];
}

__global__ __launch_bounds__(128, 2) void ode_kernel(
    const float* __restrict__ rnn,
    const float* __restrict__ w1, const float* __restrict__ b1,
    const float* __restrict__ w2, const float* __restrict__ b2,
    const float* __restrict__ w3, const float* __restrict__ b3,
    float* __restrict__ out)
{
    __shared__ float stg[64 * 128];
    const int tid = threadIdx.x;
    const int tp = blockIdx.x * 128 + tid;   // t' in [0, 510]
    const int b = blockIdx.y;
    if (tp >= TT - 1) return;

    float y[32];
    const float* src = &rnn[((size_t)b * TT + tp + 1) * ZZ];
    #pragma unroll
    for (int i = 0; i < 32; ++i) y[i] = src[i];

    const float hs = hstep();
    float ks[32], tin[32], ko[32];

    for (int it = 0; it < 9; ++it) {   // DISC-1 = 9 RK4 steps
        feval(y, ko, w1, b1, w2, b2, w3, b3, stg, tid);            // k1
        #pragma unroll
        for (int i = 0; i < 32; ++i) {
            ks[i] = ko[i];
            tin[i] = fmaf(0.5f * hs, ko[i], y[i]);
        }
        feval(tin, ko, w1, b1, w2, b2, w3, b3, stg, tid);          // k2
        #pragma unroll
        for (int i = 0; i < 32; ++i) {
            ks[i] = fmaf(2.f, ko[i], ks[i]);
            tin[i] = fmaf(0.5f * hs, ko[i], y[i]);
        }
        feval(tin, ko, w1, b1, w2, b2, w3, b3, stg, tid);          // k3
        #pragma unroll
        for (int i = 0; i < 32; ++i) {
            ks[i] = fmaf(2.f, ko[i], ks[i]);
            tin[i] = fmaf(hs, ko[i], y[i]);
        }
        feval(tin, ko, w1, b1, w2, b2, w3, b3, stg, tid);          // k4
        #pragma unroll
        for (int i = 0; i < 32; ++i) {
            y[i] = fmaf(hs / 6.f, ks[i] + ko[i], y[i]);
        }
    }

    float* dst = &out[((size_t)b * TT + tp) * ZZ];
    #pragma unroll
    for (int i = 0; i < 32; ++i) dst[i] = y[i];
}

// ---------------------------------------------------------------------------
extern "C" void kernel_launch(void* const* d_in, const int* in_sizes, int n_in,
                              void* d_out, int out_size, void* d_ws, size_t ws_size,
                              hipStream_t stream) {
    const float* x   = (const float*)d_in[0];
    const float* Wi0 = (const float*)d_in[1];
    const float* Wh0 = (const float*)d_in[2];
    const float* bi0 = (const float*)d_in[3];
    const float* bh0 = (const float*)d_in[4];
    const float* Wi1 = (const float*)d_in[5];
    const float* Wh1 = (const float*)d_in[6];
    const float* bi1 = (const float*)d_in[7];
    const float* bh1 = (const float*)d_in[8];
    const float* h0  = (const float*)d_in[9];
    const float* w1  = (const float*)d_in[10];
    const float* b1  = (const float*)d_in[11];
    const float* w2  = (const float*)d_in[12];
    const float* b2  = (const float*)d_in[13];
    const float* w3  = (const float*)d_in[14];
    const float* b3  = (const float*)d_in[15];
    float* out = (float*)d_out;
    float* rnn = (float*)d_ws;   // B*T*Z fp32 = 16 MiB scratch

    rnn_kernel<<<BB, 64, 0, stream>>>(x, Wi0, Wh0, bi0, bh0,
                                      Wi1, Wh1, bi1, bh1, h0, rnn, out);
    ode_kernel<<<dim3(4, BB), 128, 0, stream>>>(rnn, w1, b1, w2, b2, w3, b3, out);
}

// Round 3
// 664.799 us; speedup vs baseline: 3.6291x; 3.6291x over previous
//
#include <hip/hip_runtime.h>
#include <hip/hip_bf16.h>
#include <math.h>

#define BB 256
#define TT 512
#define DIN 64
#define ZZ 32
#define HH 64

typedef __attribute__((ext_vector_type(4))) float f32x4;
typedef __attribute__((ext_vector_type(8))) __bf16 bf16x8;

__device__ __forceinline__ f32x4 mfma16(bf16x8 a, bf16x8 b, f32x4 c) {
  return __builtin_amdgcn_mfma_f32_16x16x32_bf16(a, b, c, 0, 0, 0);
}

__device__ __forceinline__ float elu1(float v) {
  return v > 0.f ? v : __expf(v) - 1.f;
}
__device__ __forceinline__ f32x4 elu4(f32x4 v) {
  f32x4 r;
  r.x = elu1(v.x); r.y = elu1(v.y); r.z = elu1(v.z); r.w = elu1(v.w);
  return r;
}

// pack two f32x4 (tile0 regs, tile1 regs) into a bf16x8 MFMA operand.
// Slot (q,e) then holds value for k = 16*(e>>2) + 4q + (e&3) -- which is
// exactly the neuron held by D tiles (tile = e>>2, row = 4q + (e&3)).
__device__ __forceinline__ bf16x8 pack2(f32x4 a, f32x4 b) {
  bf16x8 r;
  r[0] = (__bf16)a.x; r[1] = (__bf16)a.y; r[2] = (__bf16)a.z; r[3] = (__bf16)a.w;
  r[4] = (__bf16)b.x; r[5] = (__bf16)b.y; r[6] = (__bf16)b.z; r[7] = (__bf16)b.w;
  return r;
}

// A-fragment gather: row rowp, k-slots (q,e) -> offsets o1+e (e<4), o2+(e-4).
__device__ __forceinline__ bf16x8 ldw(const float* rowp, int o1, int o2) {
  f32x4 a = *reinterpret_cast<const f32x4*>(rowp + o1);
  f32x4 b = *reinterpret_cast<const f32x4*>(rowp + o2);
  return pack2(a, b);
}

// ---------------------------------------------------------------------------
// RNN kernel: R0 structure (verified passing) + 2-deep register prefetch of x.
// One block (64 threads = 1 wave) per batch, sequential over T, both layers
// fused, all __syncthreads() kept.
// ---------------------------------------------------------------------------
__global__ __launch_bounds__(64) void rnn_kernel(
    const float* __restrict__ x,
    const float* __restrict__ Wi0, const float* __restrict__ Wh0,
    const float* __restrict__ bi0, const float* __restrict__ bh0,
    const float* __restrict__ Wi1, const float* __restrict__ Wh1,
    const float* __restrict__ bi1, const float* __restrict__ bh1,
    const float* __restrict__ h0,
    float* __restrict__ rnn, float* __restrict__ out)
{
    __shared__ float sWi0[32][65];
    __shared__ float sWh0[32][33];
    __shared__ float sWi1[32][33];
    __shared__ float sWh1[32][33];
    __shared__ float sB0[32], sB1[32];
    __shared__ float sx[64];
    __shared__ float sh0[32], sh1[32];

    const int lane = threadIdx.x;
    const int b = blockIdx.x;

    for (int e = lane; e < 32 * 64; e += 64) sWi0[e >> 6][e & 63] = Wi0[e];
    for (int e = lane; e < 32 * 32; e += 64) {
        sWh0[e >> 5][e & 31] = Wh0[e];
        sWi1[e >> 5][e & 31] = Wi1[e];
        sWh1[e >> 5][e & 31] = Wh1[e];
    }
    if (lane < 32) {
        sB0[lane] = bi0[lane] + bh0[lane];
        sB1[lane] = bi1[lane] + bh1[lane];
        sh0[lane] = h0[lane];
        sh1[lane] = h0[32 + lane];
    }
    __syncthreads();

    const int j = lane & 31;
    const int half = lane >> 5;
    const size_t xbase = (size_t)b * TT * DIN;
    const size_t rbase = (size_t)b * TT * ZZ;

    float xc = x[xbase + (size_t)511 * DIN + lane];
    float xn = x[xbase + (size_t)510 * DIN + lane];

    for (int s = 0; s < TT; ++s) {
        const int t = TT - 1 - s;
        sx[lane] = xc;
        float xn2 = 0.f;
        if (t >= 2) xn2 = x[xbase + (size_t)(t - 2) * DIN + lane];
        __syncthreads();

        // ---- layer 0 ----
        float a0 = 0.f, a1 = 0.f, a2 = 0.f, a3 = 0.f;
        {
            const float* wr = &sWi0[j][half * 32];
            const float* xp = &sx[half * 32];
            #pragma unroll
            for (int k = 0; k < 32; k += 4) {
                a0 = fmaf(wr[k + 0], xp[k + 0], a0);
                a1 = fmaf(wr[k + 1], xp[k + 1], a1);
                a2 = fmaf(wr[k + 2], xp[k + 2], a2);
                a3 = fmaf(wr[k + 3], xp[k + 3], a3);
            }
            const float* hr = &sWh0[j][half * 16];
            const float* hp = &sh0[half * 16];
            #pragma unroll
            for (int k = 0; k < 16; k += 4) {
                a0 = fmaf(hr[k + 0], hp[k + 0], a0);
                a1 = fmaf(hr[k + 1], hp[k + 1], a1);
                a2 = fmaf(hr[k + 2], hp[k + 2], a2);
                a3 = fmaf(hr[k + 3], hp[k + 3], a3);
            }
        }
        float acc = (a0 + a1) + (a2 + a3);
        acc += __shfl_xor(acc, 32);
        const float h0new = tanhf(acc + sB0[j]);
        __syncthreads();
        if (half == 0) sh0[j] = h0new;
        __syncthreads();

        // ---- layer 1 ----
        a0 = a1 = a2 = a3 = 0.f;
        {
            const float* wr = &sWi1[j][half * 16];
            const float* ip = &sh0[half * 16];
            #pragma unroll
            for (int k = 0; k < 16; k += 4) {
                a0 = fmaf(wr[k + 0], ip[k + 0], a0);
                a1 = fmaf(wr[k + 1], ip[k + 1], a1);
                a2 = fmaf(wr[k + 2], ip[k + 2], a2);
                a3 = fmaf(wr[k + 3], ip[k + 3], a3);
            }
            const float* hr = &sWh1[j][half * 16];
            const float* hp = &sh1[half * 16];
            #pragma unroll
            for (int k = 0; k < 16; k += 4) {
                a0 = fmaf(hr[k + 0], hp[k + 0], a0);
                a1 = fmaf(hr[k + 1], hp[k + 1], a1);
                a2 = fmaf(hr[k + 2], hp[k + 2], a2);
                a3 = fmaf(hr[k + 3], hp[k + 3], a3);
            }
        }
        acc = (a0 + a1) + (a2 + a3);
        acc += __shfl_xor(acc, 32);
        const float h1new = tanhf(acc + sB1[j]);
        __syncthreads();
        if (half == 0) {
            sh1[j] = h1new;
            rnn[rbase + (size_t)t * ZZ + j] = h1new;
            if (t == TT - 1) out[rbase + (size_t)(TT - 1) * ZZ + j] = h1new;
        }
        __syncthreads();
        xc = xn; xn = xn2;
    }
}

// ---------------------------------------------------------------------------
// ODE kernel: operand-swapped MFMA (D = W·X^T). 16 samples per wave, samples
// pinned to lane&15 across all layers, D tiles repack directly into the next
// layer's B fragment in registers. No LDS, no barriers, no shuffles.
// ---------------------------------------------------------------------------
__global__ __launch_bounds__(256, 2) void ode_kernel(
    const float* __restrict__ rnn,
    const float* __restrict__ w1, const float* __restrict__ b1,
    const float* __restrict__ w2, const float* __restrict__ b2,
    const float* __restrict__ w3, const float* __restrict__ b3,
    float* __restrict__ out)
{
  const int lane = threadIdx.x & 63;
  const int wv = threadIdx.x >> 6;
  const int q = lane >> 4, c = lane & 15;

  // ---- weight A-fragments + bias C-fragments (loaded once) ----
  bf16x8 W1[4], W2[2][4], W3[2][2];
  f32x4 BZ1[4], BZ2[4], BZ3[2];
  #pragma unroll
  for (int mt = 0; mt < 4; ++mt) {
    W1[mt] = ldw(w1 + (16 * mt + c) * 32, 4 * q, 16 + 4 * q);
    BZ1[mt] = *reinterpret_cast<const f32x4*>(b1 + 16 * mt + 4 * q);
    BZ2[mt] = *reinterpret_cast<const f32x4*>(b2 + 16 * mt + 4 * q);
  }
  #pragma unroll
  for (int kt = 0; kt < 2; ++kt)
    #pragma unroll
    for (int mt = 0; mt < 4; ++mt)
      W2[kt][mt] = ldw(w2 + (16 * mt + c) * 64, 32 * kt + 4 * q, 32 * kt + 16 + 4 * q);
  #pragma unroll
  for (int kt = 0; kt < 2; ++kt)
    #pragma unroll
    for (int mt = 0; mt < 2; ++mt)
      W3[kt][mt] = ldw(w3 + (16 * mt + c) * 64, 32 * kt + 4 * q, 32 * kt + 16 + 4 * q);
  #pragma unroll
  for (int mt = 0; mt < 2; ++mt)
    BZ3[mt] = *reinterpret_cast<const f32x4*>(b3 + 16 * mt + 4 * q);

  // ---- y state: lane holds sample (row) = 16*wave + c, dims {4q+r, 16+4q+r}
  const unsigned row = 16u * (blockIdx.x * 4u + (unsigned)wv) + (unsigned)c;
  const unsigned bb = row / 511u, tp = row - bb * 511u;
  const float* srcp = rnn + ((size_t)bb * TT + tp + 1) * ZZ;
  f32x4 y0 = *reinterpret_cast<const f32x4*>(srcp + 4 * q);
  f32x4 y1 = *reinterpret_cast<const f32x4*>(srcp + 16 + 4 * q);

  f32x4 k0, k1, ks0, ks1;

  auto feval = [&](bf16x8 xf, f32x4& o0, f32x4& o1) {
    f32x4 a[4];
    #pragma unroll
    for (int mt = 0; mt < 4; ++mt) a[mt] = mfma16(W1[mt], xf, BZ1[mt]);
    #pragma unroll
    for (int mt = 0; mt < 4; ++mt) a[mt] = elu4(a[mt]);
    bf16x8 h10 = pack2(a[0], a[1]), h11 = pack2(a[2], a[3]);
    f32x4 g[4];
    #pragma unroll
    for (int mt = 0; mt < 4; ++mt)
      g[mt] = mfma16(W2[1][mt], h11, mfma16(W2[0][mt], h10, BZ2[mt]));
    #pragma unroll
    for (int mt = 0; mt < 4; ++mt) g[mt] = elu4(g[mt]);
    bf16x8 h20 = pack2(g[0], g[1]), h21 = pack2(g[2], g[3]);
    o0 = mfma16(W3[1][0], h21, mfma16(W3[0][0], h20, BZ3[0]));
    o1 = mfma16(W3[1][1], h21, mfma16(W3[0][1], h20, BZ3[1]));
  };

  const float hs = 0.01f;
  #pragma unroll 1
  for (int it = 0; it < 9; ++it) {
    feval(pack2(y0, y1), k0, k1);                                  // k1
    ks0 = k0; ks1 = k1;
    feval(pack2(y0 + (0.5f * hs) * k0, y1 + (0.5f * hs) * k1), k0, k1);  // k2
    ks0 += 2.f * k0; ks1 += 2.f * k1;
    feval(pack2(y0 + (0.5f * hs) * k0, y1 + (0.5f * hs) * k1), k0, k1);  // k3
    ks0 += 2.f * k0; ks1 += 2.f * k1;
    feval(pack2(y0 + hs * k0, y1 + hs * k1), k0, k1);              // k4
    y0 += (hs / 6.f) * (ks0 + k0);
    y1 += (hs / 6.f) * (ks1 + k1);
  }

  float* dstp = out + ((size_t)bb * TT + tp) * ZZ;
  *reinterpret_cast<f32x4*>(dstp + 4 * q) = y0;
  *reinterpret_cast<f32x4*>(dstp + 16 + 4 * q) = y1;
}

// ---------------------------------------------------------------------------
extern "C" void kernel_launch(void* const* d_in, const int* in_sizes, int n_in,
                              void* d_out, int out_size, void* d_ws, size_t ws_size,
                              hipStream_t stream) {
  const float* x   = (const float*)d_in[0];
  const float* Wi0 = (const float*)d_in[1];
  const float* Wh0 = (const float*)d_in[2];
  const float* bi0 = (const float*)d_in[3];
  const float* bh0 = (const float*)d_in[4];
  const float* Wi1 = (const float*)d_in[5];
  const float* Wh1 = (const float*)d_in[6];
  const float* bi1 = (const float*)d_in[7];
  const float* bh1 = (const float*)d_in[8];
  const float* h0  = (const float*)d_in[9];
  const float* w1  = (const float*)d_in[10];
  const float* b1  = (const float*)d_in[11];
  const float* w2  = (const float*)d_in[12];
  const float* b2  = (const float*)d_in[13];
  const float* w3  = (const float*)d_in[14];
  const float* b3  = (const float*)d_in[15];
  float* out = (float*)d_out;
  float* rnn = (float*)d_ws;   // B*T*Z fp32 = 16.7 MB scratch

  rnn_kernel<<<BB, 64, 0, stream>>>(x, Wi0, Wh0, bi0, bh0,
                                    Wi1, Wh1, bi1, bh1, h0, rnn, out);
  // 130816 rows = 16 rows/wave * 4 waves/block * 2044 blocks (exact)
  ode_kernel<<<2044, 256, 0, stream>>>(rnn, w1, b1, w2, b2, w3, b3, out);
}

// Round 4
// 536.039 us; speedup vs baseline: 4.5008x; 1.2402x over previous
//
#include <hip/hip_runtime.h>
#include <hip/hip_bf16.h>
#include <math.h>

#define BB 256
#define TT 512
#define DIN 64
#define ZZ 32
#define HH 64

typedef __attribute__((ext_vector_type(4))) float f32x4;
typedef __attribute__((ext_vector_type(8))) __bf16 bf16x8;

__device__ __forceinline__ f32x4 mfma16(bf16x8 a, bf16x8 b, f32x4 c) {
  return __builtin_amdgcn_mfma_f32_16x16x32_bf16(a, b, c, 0, 0, 0);
}

__device__ __forceinline__ float elu1(float v) {
  return v > 0.f ? v : __expf(v) - 1.f;
}
__device__ __forceinline__ f32x4 elu4(f32x4 v) {
  f32x4 r;
  r.x = elu1(v.x); r.y = elu1(v.y); r.z = elu1(v.z); r.w = elu1(v.w);
  return r;
}

// pack two f32x4 (tile0 regs, tile1 regs) into a bf16x8 MFMA operand.
// Slot (q,e) holds value for k = 16*(e>>2) + 4q + (e&3) == neuron held by
// D tiles (tile = e>>2, row = 4q + (e&3)). Verified passing in R3.
__device__ __forceinline__ bf16x8 pack2(f32x4 a, f32x4 b) {
  bf16x8 r;
  r[0] = (__bf16)a.x; r[1] = (__bf16)a.y; r[2] = (__bf16)a.z; r[3] = (__bf16)a.w;
  r[4] = (__bf16)b.x; r[5] = (__bf16)b.y; r[6] = (__bf16)b.z; r[7] = (__bf16)b.w;
  return r;
}

// hi/lo split pack: hi = RNE bf16, lo = bf16(v - float(hi)).
__device__ __forceinline__ void packhl(f32x4 a, f32x4 b, bf16x8& hi, bf16x8& lo) {
  hi = pack2(a, b);
  f32x4 ra, rb;
  ra.x = (float)hi[0]; ra.y = (float)hi[1]; ra.z = (float)hi[2]; ra.w = (float)hi[3];
  rb.x = (float)hi[4]; rb.y = (float)hi[5]; rb.z = (float)hi[6]; rb.w = (float)hi[7];
  lo = pack2(a - ra, b - rb);
}

// A-fragment gather (row rowp; k-slots at o1+e (e<4), o2+(e-4)).
__device__ __forceinline__ bf16x8 ldw(const float* rowp, int o1, int o2) {
  f32x4 a = *reinterpret_cast<const f32x4*>(rowp + o1);
  f32x4 b = *reinterpret_cast<const f32x4*>(rowp + o2);
  return pack2(a, b);
}
__device__ __forceinline__ void ldw2(const float* rowp, int o1, int o2,
                                     bf16x8& hi, bf16x8& lo) {
  f32x4 a = *reinterpret_cast<const f32x4*>(rowp + o1);
  f32x4 b = *reinterpret_cast<const f32x4*>(rowp + o2);
  packhl(a, b, hi, lo);
}

__device__ __forceinline__ float tanh1(float x) {
  float t = __expf(2.f * x);
  return 1.f - 2.f / (t + 1.f);
}
__device__ __forceinline__ f32x4 tanh4(f32x4 v) {
  f32x4 r;
  r.x = tanh1(v.x); r.y = tanh1(v.y); r.z = tanh1(v.z); r.w = tanh1(v.w);
  return r;
}

// ---------------------------------------------------------------------------
// RNN kernel: 16 batches per wave via operand-swapped MFMA. Recurrent weights
// and h state kept as bf16 hi+lo pairs (near-fp32 recurrence, only lo*lo
// dropped); x is plain bf16, prefetched 3 steps ahead; layer-0 x-part
// precomputed one step early so each step starts at the recurrent MFMA.
// No LDS, no barriers, no shuffles.
// ---------------------------------------------------------------------------
__global__ __launch_bounds__(64, 1) void rnn_kernel(
    const float* __restrict__ x,
    const float* __restrict__ Wi0, const float* __restrict__ Wh0,
    const float* __restrict__ bi0, const float* __restrict__ bh0,
    const float* __restrict__ Wi1, const float* __restrict__ Wh1,
    const float* __restrict__ bi1, const float* __restrict__ bh1,
    const float* __restrict__ h0,
    float* __restrict__ rnn, float* __restrict__ out)
{
  const int lane = threadIdx.x & 63;
  const int q = lane >> 4, c = lane & 15;
  const int b0 = blockIdx.x * 16;

  // ---- weight A-fragments (hi/lo) ----
  bf16x8 Wi0h[2][2], Wi0l[2][2];            // [kt][mt], 32x64
  #pragma unroll
  for (int kt = 0; kt < 2; ++kt)
    #pragma unroll
    for (int mt = 0; mt < 2; ++mt)
      ldw2(Wi0 + (16 * mt + c) * 64, 32 * kt + 4 * q, 32 * kt + 16 + 4 * q,
           Wi0h[kt][mt], Wi0l[kt][mt]);
  bf16x8 Wh0h[2], Wh0l[2], Wi1h[2], Wi1l[2], Wh1h[2], Wh1l[2];   // 32x32
  #pragma unroll
  for (int mt = 0; mt < 2; ++mt) {
    ldw2(Wh0 + (16 * mt + c) * 32, 4 * q, 16 + 4 * q, Wh0h[mt], Wh0l[mt]);
    ldw2(Wi1 + (16 * mt + c) * 32, 4 * q, 16 + 4 * q, Wi1h[mt], Wi1l[mt]);
    ldw2(Wh1 + (16 * mt + c) * 32, 4 * q, 16 + 4 * q, Wh1h[mt], Wh1l[mt]);
  }
  // ---- biases in D layout (neuron = 16mt+4q+r) ----
  f32x4 B0[2], B1[2];
  #pragma unroll
  for (int mt = 0; mt < 2; ++mt) {
    B0[mt] = *reinterpret_cast<const f32x4*>(bi0 + 16 * mt + 4 * q) +
             *reinterpret_cast<const f32x4*>(bh0 + 16 * mt + 4 * q);
    B1[mt] = *reinterpret_cast<const f32x4*>(bi1 + 16 * mt + 4 * q) +
             *reinterpret_cast<const f32x4*>(bh1 + 16 * mt + 4 * q);
  }
  // ---- initial h fragments ----
  bf16x8 h0hi, h0lo, h1hi, h1lo;
  {
    f32x4 u0 = *reinterpret_cast<const f32x4*>(h0 + 4 * q);
    f32x4 u1 = *reinterpret_cast<const f32x4*>(h0 + 16 + 4 * q);
    packhl(u0, u1, h0hi, h0lo);
    u0 = *reinterpret_cast<const f32x4*>(h0 + 32 + 4 * q);
    u1 = *reinterpret_cast<const f32x4*>(h0 + 48 + 4 * q);
    packhl(u0, u1, h1hi, h1lo);
  }

  const float* px = x + (size_t)(b0 + c) * TT * DIN;
  float* pr = rnn + (size_t)(b0 + c) * TT * ZZ;
  float* po = out + (size_t)(b0 + c) * TT * ZZ;

  // ---- x pipeline: P0cur for t=511; raw A=x(510), B=x(509) ----
  f32x4 P0c0, P0c1;
  {
    const float* pt = px + (size_t)511 * DIN;
    f32x4 t0 = *reinterpret_cast<const f32x4*>(pt + 4 * q);
    f32x4 t1 = *reinterpret_cast<const f32x4*>(pt + 16 + 4 * q);
    f32x4 t2 = *reinterpret_cast<const f32x4*>(pt + 32 + 4 * q);
    f32x4 t3 = *reinterpret_cast<const f32x4*>(pt + 48 + 4 * q);
    bf16x8 xf0 = pack2(t0, t1), xf1 = pack2(t2, t3);
    P0c0 = mfma16(Wi0h[0][0], xf0, B0[0]);
    P0c0 = mfma16(Wi0l[0][0], xf0, P0c0);
    P0c0 = mfma16(Wi0h[1][0], xf1, P0c0);
    P0c0 = mfma16(Wi0l[1][0], xf1, P0c0);
    P0c1 = mfma16(Wi0h[0][1], xf0, B0[1]);
    P0c1 = mfma16(Wi0l[0][1], xf0, P0c1);
    P0c1 = mfma16(Wi0h[1][1], xf1, P0c1);
    P0c1 = mfma16(Wi0l[1][1], xf1, P0c1);
  }
  f32x4 A0, A1, A2, A3, Bv0, Bv1, Bv2, Bv3;
  {
    const float* pa = px + (size_t)510 * DIN;
    A0 = *reinterpret_cast<const f32x4*>(pa + 4 * q);
    A1 = *reinterpret_cast<const f32x4*>(pa + 16 + 4 * q);
    A2 = *reinterpret_cast<const f32x4*>(pa + 32 + 4 * q);
    A3 = *reinterpret_cast<const f32x4*>(pa + 48 + 4 * q);
    const float* pb = px + (size_t)509 * DIN;
    Bv0 = *reinterpret_cast<const f32x4*>(pb + 4 * q);
    Bv1 = *reinterpret_cast<const f32x4*>(pb + 16 + 4 * q);
    Bv2 = *reinterpret_cast<const f32x4*>(pb + 32 + 4 * q);
    Bv3 = *reinterpret_cast<const f32x4*>(pb + 48 + 4 * q);
  }

  // STEP(t, R): R holds x(t-1). Computes h(t); builds P0 for t-1 from R;
  // reloads R <- x(t-3) (next consumed at STEP(t-2)).
  auto STEP = [&](int t, f32x4& r0, f32x4& r1, f32x4& r2, f32x4& r3) {
    // layer-0 recurrent chain (on critical path)
    f32x4 a0 = mfma16(Wh0h[0], h0hi, P0c0);
    a0 = mfma16(Wh0h[0], h0lo, a0);
    a0 = mfma16(Wh0l[0], h0hi, a0);
    f32x4 a1 = mfma16(Wh0h[1], h0hi, P0c1);
    a1 = mfma16(Wh0h[1], h0lo, a1);
    a1 = mfma16(Wh0l[1], h0hi, a1);
    // layer-1 recurrent precompute (parallel to layer 0)
    f32x4 q0 = mfma16(Wh1h[0], h1hi, B1[0]);
    q0 = mfma16(Wh1h[0], h1lo, q0);
    q0 = mfma16(Wh1l[0], h1hi, q0);
    f32x4 q1 = mfma16(Wh1h[1], h1hi, B1[1]);
    q1 = mfma16(Wh1h[1], h1lo, q1);
    q1 = mfma16(Wh1l[1], h1hi, q1);
    // next-step x-part (off chain; result used next STEP)
    bf16x8 xf0 = pack2(r0, r1), xf1 = pack2(r2, r3);
    f32x4 p0 = mfma16(Wi0h[0][0], xf0, B0[0]);
    p0 = mfma16(Wi0l[0][0], xf0, p0);
    p0 = mfma16(Wi0h[1][0], xf1, p0);
    p0 = mfma16(Wi0l[1][0], xf1, p0);
    f32x4 p1 = mfma16(Wi0h[0][1], xf0, B0[1]);
    p1 = mfma16(Wi0l[0][1], xf0, p1);
    p1 = mfma16(Wi0h[1][1], xf1, p1);
    p1 = mfma16(Wi0l[1][1], xf1, p1);
    // prefetch x(t-3)
    {
      const int tl = t >= 3 ? t - 3 : 0;
      const float* pt = px + (size_t)tl * DIN;
      r0 = *reinterpret_cast<const f32x4*>(pt + 4 * q);
      r1 = *reinterpret_cast<const f32x4*>(pt + 16 + 4 * q);
      r2 = *reinterpret_cast<const f32x4*>(pt + 32 + 4 * q);
      r3 = *reinterpret_cast<const f32x4*>(pt + 48 + 4 * q);
    }
    // layer 0 activation + repack
    f32x4 d0 = tanh4(a0), d1 = tanh4(a1);
    packhl(d0, d1, h0hi, h0lo);
    // layer 1 input chain
    q0 = mfma16(Wi1h[0], h0hi, q0);
    q0 = mfma16(Wi1h[0], h0lo, q0);
    q0 = mfma16(Wi1l[0], h0hi, q0);
    q1 = mfma16(Wi1h[1], h0hi, q1);
    q1 = mfma16(Wi1h[1], h0lo, q1);
    q1 = mfma16(Wi1l[1], h0hi, q1);
    f32x4 e0 = tanh4(q0), e1 = tanh4(q1);
    float* prt = pr + (size_t)t * ZZ;
    *reinterpret_cast<f32x4*>(prt + 4 * q) = e0;
    *reinterpret_cast<f32x4*>(prt + 16 + 4 * q) = e1;
    if (t == TT - 1) {
      float* pot = po + (size_t)t * ZZ;
      *reinterpret_cast<f32x4*>(pot + 4 * q) = e0;
      *reinterpret_cast<f32x4*>(pot + 16 + 4 * q) = e1;
    }
    packhl(e0, e1, h1hi, h1lo);
    P0c0 = p0; P0c1 = p1;
  };

  #pragma unroll 1
  for (int s2 = 0; s2 < 256; ++s2) {
    const int t0 = 511 - 2 * s2;
    STEP(t0, A0, A1, A2, A3);
    STEP(t0 - 1, Bv0, Bv1, Bv2, Bv3);
  }
}

// ---------------------------------------------------------------------------
// ODE kernel: unchanged from R3 (verified passing).
// ---------------------------------------------------------------------------
__global__ __launch_bounds__(256, 2) void ode_kernel(
    const float* __restrict__ rnn,
    const float* __restrict__ w1, const float* __restrict__ b1,
    const float* __restrict__ w2, const float* __restrict__ b2,
    const float* __restrict__ w3, const float* __restrict__ b3,
    float* __restrict__ out)
{
  const int lane = threadIdx.x & 63;
  const int wv = threadIdx.x >> 6;
  const int q = lane >> 4, c = lane & 15;

  bf16x8 W1[4], W2[2][4], W3[2][2];
  f32x4 BZ1[4], BZ2[4], BZ3[2];
  #pragma unroll
  for (int mt = 0; mt < 4; ++mt) {
    W1[mt] = ldw(w1 + (16 * mt + c) * 32, 4 * q, 16 + 4 * q);
    BZ1[mt] = *reinterpret_cast<const f32x4*>(b1 + 16 * mt + 4 * q);
    BZ2[mt] = *reinterpret_cast<const f32x4*>(b2 + 16 * mt + 4 * q);
  }
  #pragma unroll
  for (int kt = 0; kt < 2; ++kt)
    #pragma unroll
    for (int mt = 0; mt < 4; ++mt)
      W2[kt][mt] = ldw(w2 + (16 * mt + c) * 64, 32 * kt + 4 * q, 32 * kt + 16 + 4 * q);
  #pragma unroll
  for (int kt = 0; kt < 2; ++kt)
    #pragma unroll
    for (int mt = 0; mt < 2; ++mt)
      W3[kt][mt] = ldw(w3 + (16 * mt + c) * 64, 32 * kt + 4 * q, 32 * kt + 16 + 4 * q);
  #pragma unroll
  for (int mt = 0; mt < 2; ++mt)
    BZ3[mt] = *reinterpret_cast<const f32x4*>(b3 + 16 * mt + 4 * q);

  const unsigned row = 16u * (blockIdx.x * 4u + (unsigned)wv) + (unsigned)c;
  const unsigned bb = row / 511u, tp = row - bb * 511u;
  const float* srcp = rnn + ((size_t)bb * TT + tp + 1) * ZZ;
  f32x4 y0 = *reinterpret_cast<const f32x4*>(srcp + 4 * q);
  f32x4 y1 = *reinterpret_cast<const f32x4*>(srcp + 16 + 4 * q);

  f32x4 k0, k1, ks0, ks1;

  auto feval = [&](bf16x8 xf, f32x4& o0, f32x4& o1) {
    f32x4 a[4];
    #pragma unroll
    for (int mt = 0; mt < 4; ++mt) a[mt] = mfma16(W1[mt], xf, BZ1[mt]);
    #pragma unroll
    for (int mt = 0; mt < 4; ++mt) a[mt] = elu4(a[mt]);
    bf16x8 h10 = pack2(a[0], a[1]), h11 = pack2(a[2], a[3]);
    f32x4 g[4];
    #pragma unroll
    for (int mt = 0; mt < 4; ++mt)
      g[mt] = mfma16(W2[1][mt], h11, mfma16(W2[0][mt], h10, BZ2[mt]));
    #pragma unroll
    for (int mt = 0; mt < 4; ++mt) g[mt] = elu4(g[mt]);
    bf16x8 h20 = pack2(g[0], g[1]), h21 = pack2(g[2], g[3]);
    o0 = mfma16(W3[1][0], h21, mfma16(W3[0][0], h20, BZ3[0]));
    o1 = mfma16(W3[1][1], h21, mfma16(W3[0][1], h20, BZ3[1]));
  };

  const float hs = 0.01f;
  #pragma unroll 1
  for (int it = 0; it < 9; ++it) {
    feval(pack2(y0, y1), k0, k1);
    ks0 = k0; ks1 = k1;
    feval(pack2(y0 + (0.5f * hs) * k0, y1 + (0.5f * hs) * k1), k0, k1);
    ks0 += 2.f * k0; ks1 += 2.f * k1;
    feval(pack2(y0 + (0.5f * hs) * k0, y1 + (0.5f * hs) * k1), k0, k1);
    ks0 += 2.f * k0; ks1 += 2.f * k1;
    feval(pack2(y0 + hs * k0, y1 + hs * k1), k0, k1);
    y0 += (hs / 6.f) * (ks0 + k0);
    y1 += (hs / 6.f) * (ks1 + k1);
  }

  float* dstp = out + ((size_t)bb * TT + tp) * ZZ;
  *reinterpret_cast<f32x4*>(dstp + 4 * q) = y0;
  *reinterpret_cast<f32x4*>(dstp + 16 + 4 * q) = y1;
}

// ---------------------------------------------------------------------------
extern "C" void kernel_launch(void* const* d_in, const int* in_sizes, int n_in,
                              void* d_out, int out_size, void* d_ws, size_t ws_size,
                              hipStream_t stream) {
  const float* x   = (const float*)d_in[0];
  const float* Wi0 = (const float*)d_in[1];
  const float* Wh0 = (const float*)d_in[2];
  const float* bi0 = (const float*)d_in[3];
  const float* bh0 = (const float*)d_in[4];
  const float* Wi1 = (const float*)d_in[5];
  const float* Wh1 = (const float*)d_in[6];
  const float* bi1 = (const float*)d_in[7];
  const float* bh1 = (const float*)d_in[8];
  const float* h0  = (const float*)d_in[9];
  const float* w1  = (const float*)d_in[10];
  const float* b1  = (const float*)d_in[11];
  const float* w2  = (const float*)d_in[12];
  const float* b2  = (const float*)d_in[13];
  const float* w3  = (const float*)d_in[14];
  const float* b3  = (const float*)d_in[15];
  float* out = (float*)d_out;
  float* rnn = (float*)d_ws;   // B*T*Z fp32 = 16.7 MB scratch

  // 256 batches = 16 batches/wave * 16 blocks
  rnn_kernel<<<16, 64, 0, stream>>>(x, Wi0, Wh0, bi0, bh0,
                                    Wi1, Wh1, bi1, bh1, h0, rnn, out);
  // 130816 rows = 16 rows/wave * 4 waves/block * 2044 blocks (exact)
  ode_kernel<<<2044, 256, 0, stream>>>(rnn, w1, b1, w2, b2, w3, b3, out);
}